// Round 1
// baseline (646.430 us; speedup 1.0000x reference)
//
#include <hip/hip_runtime.h>
#include <hip/hip_bf16.h>
#include <math.h>

typedef __attribute__((ext_vector_type(8))) short s16x8;
typedef __attribute__((ext_vector_type(4))) float f32x4;

static __device__ __forceinline__ float bf2f(unsigned short u){
    unsigned int x = ((unsigned int)u) << 16; float f; __builtin_memcpy(&f,&x,4); return f;
}
static __device__ __forceinline__ unsigned short f2bf(float f){
    unsigned int x; __builtin_memcpy(&x,&f,4);
    unsigned int r = (x + 0x7FFFu + ((x>>16)&1u)) >> 16; return (unsigned short)r;
}

static __device__ __forceinline__ void stage16(const void* g, void* l){
    __builtin_amdgcn_global_load_lds((const __attribute__((address_space(1))) unsigned int*)g,
                                     (__attribute__((address_space(3))) unsigned int*)l, 16, 0, 0);
}

// ---------------- sizes ----------------
// N=64, C=128, T=128, V=25, S=3, K=7
// JN = T*V = 3200, NTV = 204800, PADROW = (T+6)*25 = 3350, SC = 384, KK = 2688

// ---------------- prep ----------------
__global__ void prep_kernel(const float* __restrict__ out_w, const float* __restrict__ v_w,
                            const float* __restrict__ ff_w,
                            const float* __restrict__ out_b, const float* __restrict__ out_g,
                            const float* __restrict__ out_be, const float* __restrict__ out_m,
                            const float* __restrict__ out_v,
                            const float* __restrict__ ff_b, const float* __restrict__ ff_g,
                            const float* __restrict__ ff_be, const float* __restrict__ ff_m,
                            const float* __restrict__ ff_v,
                            float* __restrict__ G, float* __restrict__ consts,
                            unsigned short* __restrict__ Wr, unsigned short* __restrict__ vwb,
                            unsigned short* __restrict__ ffA, unsigned short* __restrict__ ypad)
{
    int stride = gridDim.x*blockDim.x;
    int i0 = blockIdx.x*blockDim.x + threadIdx.x;
    for (int i=i0; i<40000; i+=stride) G[i] = 0.f;
    for (int i=i0; i<344064; i+=stride){
        int o = i/2688, kk = i%2688;
        int k = kk/384, sc = kk%384;
        Wr[i] = f2bf(out_w[(o*384+sc)*7 + k]);
    }
    for (int i=i0; i<16384; i+=stride) vwb[i] = f2bf(v_w[i]);
    for (int i=i0; i<16384; i+=stride) ffA[i] = f2bf(ff_w[i]);
    for (int i=i0; i<128; i+=stride){
        float inv  = out_g[i]/sqrtf(out_v[i]+1e-5f);
        consts[i]       = inv;
        consts[128+i]   = out_b[i]*inv + out_be[i] - out_m[i]*inv;
        float invf = ff_g[i]/sqrtf(ff_v[i]+1e-5f);
        consts[256+i]   = invf;
        consts[384+i]   = ff_b[i]*invf + ff_be[i] - ff_m[i]*invf;
    }
    // zero the temporal halo pads of Ypad: positions [0,75) and [3275,3350) per (n)
    for (int i=i0; i<3686400; i+=stride){
        int n2 = i/57600, r2 = i%57600;
        int pp = r2/384, sc = r2%384;
        int ppos = (pp < 75) ? pp : (3200 + pp);   // -> [3275,3350)
        ypad[(size_t)(n2*3350 + ppos)*384 + sc] = 0;
    }
}

// ---------------- x transpose: x[n][c][jn] fp32 -> xbt[n][jn][c] bf16 ----------------
__global__ __launch_bounds__(256) void xt_kernel(const float* __restrict__ x, unsigned short* __restrict__ xbt){
    __shared__ float tile[32][33];
    int bid = blockIdx.x;
    int jb = bid % 100; int cb = (bid/100) & 3; int n = bid/400;
    int tx = threadIdx.x & 31, ty = threadIdx.x >> 5;
    size_t xbase = (size_t)n*409600;
    #pragma unroll
    for (int r=ty; r<32; r+=8)
        tile[r][tx] = x[xbase + (size_t)(cb*32+r)*3200 + jb*32 + tx];
    __syncthreads();
    #pragma unroll
    for (int r=ty; r<32; r+=8)
        xbt[xbase + (size_t)(jb*32+r)*128 + cb*32 + tx] = f2bf(tile[tx][r]);
}

// ---------------- gram: G[n][u][v] = sum_{c,t} (x+pe)[c,t,u]*(x+pe)[c,t,v] ----------------
__global__ __launch_bounds__(640) void gram_kernel(const float* __restrict__ x, float* __restrict__ G){
    __shared__ float yl[128][26];
    int bid = blockIdx.x; int n = bid >> 4; int chunk = bid & 15;
    int tid = threadIdx.x;
    int u = tid/25, vv = tid%25;
    float accv = 0.f;
    for (int g=0; g<8; ++g){
        int c = chunk*8 + g;
        float freq = expf(-(float)(c & ~1) * (9.210340371976184f/128.f)); // ln(1e4)=9.2103...
        __syncthreads();
        for (int e=tid; e<3200; e+=640){
            int v = e % 25;
            float ang = (float)v * freq;
            float pe = (c & 1) ? cosf(ang) : sinf(ang);
            yl[e/25][v] = x[(size_t)n*409600 + (size_t)c*3200 + e] + pe;
        }
        __syncthreads();
        if (tid < 625){
            #pragma unroll 4
            for (int t=0; t<128; ++t) accv += yl[t][u]*yl[t][vv];
        }
    }
    if (tid < 625) atomicAdd(&G[n*625 + tid], accv);
}

// ---------------- attention: global max + sparsemax ----------------
__global__ __launch_bounds__(1024) void attn_kernel(const float* __restrict__ G, const float* __restrict__ theta,
                                                    const float* __restrict__ atts, const float* __restrict__ alphas,
                                                    float* __restrict__ att){
    __shared__ float red[1024];
    int tid = threadIdx.x;
    float mx = 0.f;
    for (int idx=tid; idx<40000; idx+=1024){
        int n = idx/625, r = idx%625, u2 = r/25, v2 = r%25;
        const float* Gn = G + n*625;
        float d2v = fmaxf(Gn[u2*26] + Gn[v2*26] - 2.f*Gn[u2*25+v2], 0.f);
        mx = fmaxf(mx, d2v);
    }
    red[tid] = mx; __syncthreads();
    for (int s2=512; s2>0; s2>>=1){ if (tid < s2) red[tid] = fmaxf(red[tid], red[tid+s2]); __syncthreads(); }
    float inv = 1.f/red[0];
    for (int col=tid; col<4800; col+=1024){
        int n = col/75, r = col%75, s = r/25, vc = r%25;
        const float* Gn = G + n*625;
        float et = expf(theta[s]);
        float al = alphas[s];
        float gvv = Gn[vc*26];
        float z[25];
        #pragma unroll
        for (int u2=0; u2<25; ++u2){
            float d2v = fmaxf(Gn[u2*26] + gvv - 2.f*Gn[u2*25+vc], 0.f);
            z[u2] = expf(-et*d2v*inv);
        }
        float zm = z[0];
        #pragma unroll
        for (int u2=1; u2<25; ++u2) zm = fmaxf(zm, z[u2]);
        float lo = zm - 1.f, hi = zm;
        for (int it=0; it<30; ++it){
            float mid = 0.5f*(lo+hi);
            float f = 0.f;
            #pragma unroll
            for (int u2=0; u2<25; ++u2) f += fmaxf(z[u2]-mid, 0.f);
            if (f >= 1.f) lo = mid; else hi = mid;
        }
        float ssum = 0.f; int kcnt = 0;
        #pragma unroll
        for (int u2=0; u2<25; ++u2){ if (z[u2] > lo){ ssum += z[u2]; kcnt++; } }
        float tau = (ssum - 1.f)/(float)kcnt;
        #pragma unroll
        for (int u2=0; u2<25; ++u2)
            att[n*1875 + s*625 + u2*25 + vc] = atts[s*625 + u2*25 + vc] + fmaxf(z[u2]-tau, 0.f)*al;
    }
}

// ---------------- aggregation: y1[n,sc,t,v] = sum_u vx[c,n,t,u]*att[n,s,u,v] -> Ypad ----------------
__global__ __launch_bounds__(128) void agg_kernel(const unsigned short* __restrict__ vxb,
                                                  const float* __restrict__ att,
                                                  unsigned short* __restrict__ ypad){
    __shared__ float attl[1875];
    int bid = blockIdx.x; int n = bid >> 7; int t = bid & 127;
    int tid = threadIdx.x;  // = c
    for (int i=tid; i<1875; i+=128) attl[i] = att[n*1875 + i];
    __syncthreads();
    float p[25];
    size_t base = (size_t)tid*204800 + n*3200 + t*25;
    #pragma unroll
    for (int u2=0; u2<25; ++u2) p[u2] = bf2f(vxb[base + u2]);
    size_t obase = ((size_t)(n*3350 + 75 + t*25))*384 + tid;
    #pragma unroll
    for (int s=0; s<3; ++s){
        #pragma unroll 5
        for (int v2=0; v2<25; ++v2){
            float acc2 = 0.f;
            #pragma unroll
            for (int u2=0; u2<25; ++u2) acc2 += p[u2]*attl[s*625 + u2*25 + v2];
            ypad[obase + (size_t)v2*384 + s*128] = f2bf(acc2);
        }
    }
}

// ---------------- unified MFMA GEMM, 128x128 tile, BK=64 ----------------
// MODE 0: vx = vwb @ xbt     (+v_b)            -> vxb bf16 [o][ntv]
// MODE 1: conv = Wr @ Ypad   (BN+res+leaky)    -> zb  bf16 [ntv][o]  (LDS transpose)
// MODE 2: ff  = ffA @ zb     (BN+res+leaky)    -> out fp32 [n][co][tv]
template<int MODE, int KTOT>
__global__ __launch_bounds__(256,2) void gemm_k(const unsigned short* __restrict__ Amat,
                                                const unsigned short* __restrict__ Bsrc,
                                                const float* __restrict__ xin,
                                                const float* __restrict__ consts,
                                                unsigned short* __restrict__ outb,
                                                float* __restrict__ outf)
{
    constexpr int NKB = KTOT/64;
    constexpr int SMEMN = (MODE==1) ? 128*136 : 128*128;
    __shared__ unsigned short smem[SMEMN];
    unsigned short* sA = smem;
    unsigned short* sB = smem + 8192;

    const int tid = threadIdx.x;
    const int bid = blockIdx.x;
    const int n   = bid/25;
    const int jn0 = (bid%25)*128;
    const int j0  = bid*128;

    const int lane = tid & 63, wv = tid >> 6;
    const int wm = wv >> 1, wn = wv & 1;
    const int lr = lane & 15, lg = lane >> 4;

    f32x4 acc[4][4];
    #pragma unroll
    for (int a=0;a<4;a++)
        #pragma unroll
        for (int b=0;b<4;b++) acc[a][b] = (f32x4){0.f,0.f,0.f,0.f};

    for (int kb=0; kb<NKB; ++kb){
        #pragma unroll
        for (int p=0; p<4; ++p){
            int e = (p*256 + tid)*8;
            int r = e >> 6, kof = e & 63;
            const unsigned short* ga = Amat + (size_t)r*KTOT + kb*64 + kof;
            stage16(ga, &sA[e]);
            const unsigned short* gb;
            if constexpr (MODE==1){
                int k = kb/6; int scb = (kb%6)*64;
                gb = Bsrc + (size_t)(n*3350 + jn0 + r + 25*k)*384 + scb + kof;
            } else {
                gb = Bsrc + (size_t)(j0 + r)*128 + kb*64 + kof;
            }
            stage16(gb, &sB[e]);
        }
        __syncthreads();
        #pragma unroll
        for (int kf=0; kf<2; ++kf){
            s16x8 af[4], bfv[4];
            #pragma unroll
            for (int mf=0; mf<4; ++mf) af[mf]  = *(const s16x8*)&sA[(wm*64+mf*16+lr)*64 + kf*32 + lg*8];
            #pragma unroll
            for (int nf=0; nf<4; ++nf) bfv[nf] = *(const s16x8*)&sB[(wn*64+nf*16+lr)*64 + kf*32 + lg*8];
            #pragma unroll
            for (int mf=0; mf<4; ++mf)
                #pragma unroll
                for (int nf=0; nf<4; ++nf)
                    acc[mf][nf] = __builtin_amdgcn_mfma_f32_16x16x32_bf16(af[mf], bfv[nf], acc[mf][nf], 0, 0, 0);
        }
        __syncthreads();
    }

    if constexpr (MODE==0){
        #pragma unroll
        for (int mf=0; mf<4; ++mf)
            #pragma unroll
            for (int r=0; r<4; ++r){
                int m = wm*64 + mf*16 + lg*4 + r;
                float vbv = consts[m];
                #pragma unroll
                for (int nf=0; nf<4; ++nf){
                    int cj = wn*64 + nf*16 + lr;
                    outb[(size_t)m*204800 + j0 + cj] = f2bf(acc[mf][nf][r] + vbv);
                }
            }
    } else if constexpr (MODE==1){
        #pragma unroll
        for (int mf=0; mf<4; ++mf)
            #pragma unroll
            for (int r=0; r<4; ++r){
                int m = wm*64 + mf*16 + lg*4 + r;
                float sc = consts[m], bi = consts[128+m];
                #pragma unroll
                for (int nf=0; nf<4; ++nf){
                    int cj = wn*64 + nf*16 + lr;
                    float val = acc[mf][nf][r]*sc + bi + xin[(size_t)n*409600 + (size_t)m*3200 + jn0 + cj];
                    val = (val >= 0.f) ? val : 0.1f*val;
                    smem[cj*136 + m] = f2bf(val);
                }
            }
        __syncthreads();
        unsigned int* zb32 = (unsigned int*)outb;
        #pragma unroll
        for (int it=0; it<32; ++it){
            int w2 = it*256 + tid;
            int rr = w2 >> 6, c2 = w2 & 63;
            unsigned int word = *(const unsigned int*)&smem[rr*136 + c2*2];
            zb32[(size_t)(j0+rr)*64 + c2] = word;
        }
    } else {
        #pragma unroll
        for (int mf=0; mf<4; ++mf)
            #pragma unroll
            for (int r=0; r<4; ++r){
                int m = wm*64 + mf*16 + lg*4 + r;
                float sc = consts[256+m], bi = consts[384+m];
                #pragma unroll
                for (int nf=0; nf<4; ++nf){
                    int cj = wn*64 + nf*16 + lr;
                    size_t idx = (size_t)n*409600 + (size_t)m*3200 + jn0 + cj;
                    float val = acc[mf][nf][r]*sc + bi + xin[idx];
                    val = (val >= 0.f) ? val : 0.1f*val;
                    outf[idx] = val;
                }
            }
    }
}

extern "C" void kernel_launch(void* const* d_in, const int* in_sizes, int n_in,
                              void* d_out, int out_size, void* d_ws, size_t ws_size,
                              hipStream_t stream) {
    const float* x      = (const float*)d_in[0];
    const float* theta  = (const float*)d_in[1];
    const float* atts   = (const float*)d_in[2];
    const float* alphas = (const float*)d_in[3];
    const float* v_w    = (const float*)d_in[4];
    const float* v_b    = (const float*)d_in[5];
    const float* out_w  = (const float*)d_in[6];
    const float* out_b  = (const float*)d_in[7];
    const float* out_g  = (const float*)d_in[8];
    const float* out_be = (const float*)d_in[9];
    const float* out_m  = (const float*)d_in[10];
    const float* out_v  = (const float*)d_in[11];
    const float* ff_w   = (const float*)d_in[12];
    const float* ff_b   = (const float*)d_in[13];
    const float* ff_g   = (const float*)d_in[14];
    const float* ff_be  = (const float*)d_in[15];
    const float* ff_m   = (const float*)d_in[16];
    const float* ff_v   = (const float*)d_in[17];
    float* out = (float*)d_out;

    char* w = (char*)d_ws;
    size_t off = 0;
    auto alloc = [&](size_t b){ size_t r = off; off += (b + 1023) & ~(size_t)1023; return r; };
    float*          G      = (float*)         (w + alloc(160000));      // 64*625 f32
    float*          attbuf = (float*)         (w + alloc(480000));      // 64*1875 f32
    float*          consts = (float*)         (w + alloc(2048));        // 512 f32
    unsigned short* Wr     = (unsigned short*)(w + alloc(688128));      // 128*2688 bf16
    unsigned short* vwb    = (unsigned short*)(w + alloc(32768));
    unsigned short* ffA    = (unsigned short*)(w + alloc(32768));
    unsigned short* xbt    = (unsigned short*)(w + alloc(52428800));    // [n][tv][c] bf16
    unsigned short* vxb    = (unsigned short*)(w + alloc(52428800));    // [o][ntv] bf16
    unsigned short* ypad   = (unsigned short*)(w + alloc(164659200));   // [n][3350][384] bf16
    unsigned short* zb     = xbt;                                        // overlay: xbt dead after GEMM-V

    prep_kernel<<<2048,256,0,stream>>>(out_w, v_w, ff_w, out_b, out_g, out_be, out_m, out_v,
                                       ff_b, ff_g, ff_be, ff_m, ff_v,
                                       G, consts, Wr, vwb, ffA, ypad);
    xt_kernel<<<25600,256,0,stream>>>(x, xbt);
    gram_kernel<<<1024,640,0,stream>>>(x, G);
    attn_kernel<<<1,1024,0,stream>>>(G, theta, atts, alphas, attbuf);
    gemm_k<0,128><<<1600,256,0,stream>>>(vwb, xbt, nullptr, v_b, vxb, nullptr);
    agg_kernel<<<8192,128,0,stream>>>(vxb, attbuf, ypad);
    gemm_k<1,2688><<<1600,256,0,stream>>>(Wr, ypad, x, consts, zb, nullptr);
    gemm_k<2,128><<<1600,256,0,stream>>>(ffA, zb, x, consts, nullptr, out);
}